// Round 2
// baseline (655.622 us; speedup 1.0000x reference)
//
#include <hip/hip_runtime.h>
#include <cmath>

// Problem constants (match reference)
#define B_TOTAL 262144
#define D 16
#define TE 3
#define H 64
#define BLOCK 256
#define JC 16   // layer-2 j-chunk: caps live accumulators at 16

// softplus(x) = max(x,0) + ln2 * log2(1 + 2^(-|x| * log2e))
// 7 VALU ops, 2 transcendental (v_exp_f32, v_log_f32).
__device__ __forceinline__ float softplus_f(float x) {
    const float nax = -fabsf(x) * 1.44269504088896f;       // -|x| * log2(e)
    const float e   = __builtin_amdgcn_exp2f(nax);         // e^{-|x|}
    const float lg  = __builtin_amdgcn_logf(1.0f + e);     // log2(1 + e^{-|x|})
    return fmaf(0.693147180559945f, lg, fmaxf(x, 0.0f));
}

// Block = 256 threads over b; blockIdx.y = d (wave-uniform) so every weight
// address is uniform -> compiler scalarizes to s_load and folds weights into
// v_fmac as SGPR operands. __launch_bounds__(256,4): 4 waves/EU -> VGPR cap
// 128, enough for h1[64] + acc[16] + temps (~90) without spilling.
__global__ __launch_bounds__(BLOCK, 4) void DiagonalVariance_kernel(
    const float* __restrict__ t,   // [B, TE]
    const float* __restrict__ y,   // [B, D]
    const float* __restrict__ W1,  // [D, 1+TE, H]
    const float* __restrict__ b1,  // [D, H]
    const float* __restrict__ W2,  // [D, H, H]
    const float* __restrict__ b2,  // [D, H]
    const float* __restrict__ W3,  // [D, H, 1]
    const float* __restrict__ b3,  // [D, 1]
    float* __restrict__ out)       // [B, D]
{
    const int d = blockIdx.y;
    const int b = blockIdx.x * BLOCK + (int)threadIdx.x;

    const float x0 = y[b * D + d];
    const float t0 = t[b * TE + 0];
    const float t1 = t[b * TE + 1];
    const float t2 = t[b * TE + 2];

    const float* __restrict__ W1d = W1 + d * ((1 + TE) * H);
    const float* __restrict__ b1d = b1 + d * H;
    const float* __restrict__ W2d = W2 + d * (H * H);
    const float* __restrict__ b2d = b2 + d * H;
    const float* __restrict__ W3d = W3 + d * H;

    // ---- Layer 1 + softplus: h1[64] in registers (read-only afterwards) ----
    float h1[H];
    #pragma unroll
    for (int k = 0; k < H; ++k) {
        float pre = b1d[k];
        pre = fmaf(x0, W1d[0 * H + k], pre);
        pre = fmaf(t0, W1d[1 * H + k], pre);
        pre = fmaf(t1, W1d[2 * H + k], pre);
        pre = fmaf(t2, W1d[3 * H + k], pre);
        h1[k] = softplus_f(pre);
    }

    // ---- Layer 2 (j-chunked) + softplus + layer 3 dot, fused ----
    float acc3 = b3[d];
    #pragma unroll 1
    for (int jc = 0; jc < H; jc += JC) {       // 4 chunks; jc is wave-uniform
        float acc[JC];
        #pragma unroll
        for (int j = 0; j < JC; ++j) acc[j] = b2d[jc + j];

        // k fully unrolled so h1[k] and acc[j] are static-register indexed.
        #pragma unroll
        for (int k = 0; k < H; ++k) {
            const float h1k = h1[k];
            const float* __restrict__ w2row = W2d + k * H + jc; // 16 consecutive floats, uniform
            #pragma unroll
            for (int j = 0; j < JC; ++j) {
                acc[j] = fmaf(h1k, w2row[j], acc[j]);
            }
        }

        // epilogue for this chunk: softplus then layer-3 partial dot
        #pragma unroll
        for (int j = 0; j < JC; ++j) {
            acc3 = fmaf(softplus_f(acc[j]), W3d[jc + j], acc3);
        }
    }

    out[b * D + d] = softplus_f(acc3);
}

extern "C" void kernel_launch(void* const* d_in, const int* in_sizes, int n_in,
                              void* d_out, int out_size, void* d_ws, size_t ws_size,
                              hipStream_t stream) {
    const float* t  = (const float*)d_in[0];
    const float* y  = (const float*)d_in[1];
    const float* W1 = (const float*)d_in[2];
    const float* b1 = (const float*)d_in[3];
    const float* W2 = (const float*)d_in[4];
    const float* b2 = (const float*)d_in[5];
    const float* W3 = (const float*)d_in[6];
    const float* b3 = (const float*)d_in[7];
    float* out = (float*)d_out;

    dim3 grid(B_TOTAL / BLOCK, D);
    DiagonalVariance_kernel<<<grid, dim3(BLOCK), 0, stream>>>(
        t, y, W1, b1, W2, b2, W3, b3, out);
}

// Round 3
// 241.007 us; speedup vs baseline: 2.7203x; 2.7203x over previous
//
#include <hip/hip_runtime.h>
#include <cmath>

// Problem constants
#define B_TOTAL 262144
#define D 16
#define TE 3
#define H 64

#define TILES_PER_BLOCK 16   // b-tiles of 16 rows per block
#define FLUSH_GROUP 4        // tiles between coalesced output flushes
#define NBLOCKS (B_TOTAL / 16 / TILES_PER_BLOCK)   // 1024

#define LOG2E 1.44269504088896340736f
#define LN2   0.693147180559945309417f

typedef _Float16 half8 __attribute__((ext_vector_type(8)));
typedef float    f32x4 __attribute__((ext_vector_type(4)));

// log2(1 + 2^xs): the whole hidden softplus after folding scales into the
// weights (W1,b1,b2 pre-scaled by log2e; W3 by ln2; ln2*log2e == 1 so W2 raw).
__device__ __forceinline__ float sp_log2(float xs) {
    return __builtin_amdgcn_logf(1.0f + __builtin_amdgcn_exp2f(xs));
}
// full softplus for the final output (unscaled input), stable form
__device__ __forceinline__ float softplus_full(float x) {
    float e = __builtin_amdgcn_exp2f(-fabsf(x) * LOG2E);
    return fmaxf(x, 0.0f) + LN2 * __builtin_amdgcn_logf(1.0f + e);
}

// 16 waves/block, wave w handles dim d=w. Each iteration: one 16-row b-tile
// through the whole MLP on the MFMA pipe; outputs staged in LDS and flushed
// as contiguous 1KB lines (full-cacheline writes, no RMW).
__global__ __launch_bounds__(1024, 4) void DiagonalVariance_kernel(
    const float* __restrict__ t,   // [B, TE]
    const float* __restrict__ y,   // [B, D]
    const float* __restrict__ W1,  // [D, 4, 64]
    const float* __restrict__ b1,  // [D, 64]
    const float* __restrict__ W2,  // [D, 64, 64]
    const float* __restrict__ b2,  // [D, 64]
    const float* __restrict__ W3,  // [D, 64, 1]
    const float* __restrict__ b3,  // [D, 1]
    float* __restrict__ out)       // [B, D]
{
    // H1 transpose buffer: per wave 16 rows x 72 f16 (pad 64->72 breaks the
    // 128B-stride bank aliasing; 2-way residual conflicts are free).
    __shared__ __align__(16) _Float16 h1buf[D * 16 * 72];  // 36 KB
    __shared__ float obuf[FLUSH_GROUP * 256];              // 4 KB

    const int wave = threadIdx.x >> 6;   // = d
    const int lane = threadIdx.x & 63;
    const int q    = lane >> 4;          // quad
    const int lm   = lane & 15;
    const int d    = wave;

    const float* __restrict__ W1d = W1 + d * (4 * H);
    const float* __restrict__ b1d = b1 + d * H;
    const float* __restrict__ W2d = W2 + d * (H * H);
    const float* __restrict__ b2d = b2 + d * H;
    const float* __restrict__ W3d = W3 + d * H;

    // ---- one-time per-wave fragment setup ----
    // W2 B-frags: B[n=lm+16nt][k=32ks+8q+j], raw weights (scales cancel).
    half8 w2f[2][4];
    #pragma unroll
    for (int ks = 0; ks < 2; ++ks)
        #pragma unroll
        for (int nt = 0; nt < 4; ++nt)
            #pragma unroll
            for (int j = 0; j < 8; ++j)
                w2f[ks][nt][j] = (_Float16)W2d[(32 * ks + 8 * q + j) * H + 16 * nt + lm];

    // W1 B-frags: k = i-dim (only k<4 real, rest zero-padded), scaled by log2e.
    half8 w1f[4];
    #pragma unroll
    for (int nt = 0; nt < 4; ++nt) {
        #pragma unroll
        for (int j = 0; j < 8; ++j) {
            float v = (q == 0 && j < 4) ? W1d[j * H + 16 * nt + lm] * LOG2E : 0.0f;
            w1f[nt][j] = (_Float16)v;
        }
    }

    float b1n[4], b2n[4], w3n[4];
    #pragma unroll
    for (int nt = 0; nt < 4; ++nt) {
        b1n[nt] = b1d[16 * nt + lm] * LOG2E;   // folded into layer-1 acc init
        b2n[nt] = b2d[16 * nt + lm] * LOG2E;   // folded into layer-2 acc init
        w3n[nt] = W3d[16 * nt + lm] * LN2;     // carries H2's ln2
    }
    const float b3v = b3[d];

    _Float16* __restrict__ myH1 = h1buf + wave * (16 * 72);

    #pragma unroll 1
    for (int g = 0; g < TILES_PER_BLOCK / FLUSH_GROUP; ++g) {
        #pragma unroll 1
        for (int tg = 0; tg < FLUSH_GROUP; ++tg) {
            const int tile = blockIdx.x * TILES_PER_BLOCK + g * FLUSH_GROUP + tg;
            const int row  = tile * 16 + lm;

            // ---- x A-frag: k slots [y, t0, t1, t2, 0...], only quad 0 ----
            const float x0 = y[row * D + d];
            const float t0 = t[row * TE + 0];
            const float t1 = t[row * TE + 1];
            const float t2 = t[row * TE + 2];
            half8 af;
            #pragma unroll
            for (int j = 0; j < 8; ++j) af[j] = (_Float16)0.0f;
            if (q == 0) {
                af[0] = (_Float16)x0; af[1] = (_Float16)t0;
                af[2] = (_Float16)t1; af[3] = (_Float16)t2;
            }

            // ---- layer 1 MFMA: acc1 = (x*W1 + b1)*log2e ----
            f32x4 acc1[4];
            #pragma unroll
            for (int nt = 0; nt < 4; ++nt) {
                acc1[nt] = (f32x4){b1n[nt], b1n[nt], b1n[nt], b1n[nt]};
                acc1[nt] = __builtin_amdgcn_mfma_f32_16x16x32_f16(af, w1f[nt], acc1[nt], 0, 0, 0);
            }

            // ---- softplus (log2 domain) + LDS transpose to A-layout ----
            // C-layout: row=q*4+r (b-row), col=lm+16nt (hidden k)
            #pragma unroll
            for (int nt = 0; nt < 4; ++nt)
                #pragma unroll
                for (int r = 0; r < 4; ++r) {
                    float L = sp_log2(acc1[nt][r]);
                    myH1[(q * 4 + r) * 72 + 16 * nt + lm] = (_Float16)L;
                }

            // ---- layer 2 MFMA: A[m=lm][k=32ks+8q+j] from LDS ----
            half8 a2[2];
            #pragma unroll
            for (int ks = 0; ks < 2; ++ks)
                a2[ks] = *(const half8*)(myH1 + lm * 72 + 32 * ks + 8 * q);

            f32x4 acc2[4];
            #pragma unroll
            for (int nt = 0; nt < 4; ++nt)
                acc2[nt] = (f32x4){b2n[nt], b2n[nt], b2n[nt], b2n[nt]};
            #pragma unroll
            for (int ks = 0; ks < 2; ++ks)
                #pragma unroll
                for (int nt = 0; nt < 4; ++nt)
                    acc2[nt] = __builtin_amdgcn_mfma_f32_16x16x32_f16(a2[ks], w2f[ks][nt], acc2[nt], 0, 0, 0);

            // ---- softplus + layer-3 dot (W3 carries ln2) ----
            float s[4] = {0.0f, 0.0f, 0.0f, 0.0f};
            #pragma unroll
            for (int nt = 0; nt < 4; ++nt)
                #pragma unroll
                for (int r = 0; r < 4; ++r) {
                    float L = sp_log2(acc2[nt][r]);
                    s[r] = fmaf(L, w3n[nt], s[r]);
                }

            // butterfly sum across the 16 lanes of each quad (cols 0..63)
            #pragma unroll
            for (int mask = 1; mask < 16; mask <<= 1)
                #pragma unroll
                for (int r = 0; r < 4; ++r)
                    s[r] += __shfl_xor(s[r], mask, 64);

            // lane lm<4 stages row q*4+lm
            float v01 = (lm & 1) ? s[1] : s[0];
            float v23 = (lm & 1) ? s[3] : s[2];
            float vs  = (lm & 2) ? v23 : v01;
            float ov  = softplus_full(vs + b3v);
            if (lm < 4)
                obuf[tg * 256 + (q * 4 + lm) * D + d] = ov;
        }

        __syncthreads();
        // coalesced flush: 1024 contiguous f32 == 16 rows x 16 d x 4 tiles
        out[blockIdx.x * (TILES_PER_BLOCK * 256) + g * 1024 + threadIdx.x] = obuf[threadIdx.x];
        __syncthreads();
    }
}

extern "C" void kernel_launch(void* const* d_in, const int* in_sizes, int n_in,
                              void* d_out, int out_size, void* d_ws, size_t ws_size,
                              hipStream_t stream) {
    const float* t  = (const float*)d_in[0];
    const float* y  = (const float*)d_in[1];
    const float* W1 = (const float*)d_in[2];
    const float* b1 = (const float*)d_in[3];
    const float* W2 = (const float*)d_in[4];
    const float* b2 = (const float*)d_in[5];
    const float* W3 = (const float*)d_in[6];
    const float* b3 = (const float*)d_in[7];
    float* out = (float*)d_out;

    DiagonalVariance_kernel<<<dim3(NBLOCKS), dim3(1024), 0, stream>>>(
        t, y, W1, b1, W2, b2, W3, b3, out);
}

// Round 5
// 228.298 us; speedup vs baseline: 2.8718x; 1.0557x over previous
//
#include <hip/hip_runtime.h>
#include <cmath>

// Problem constants
#define B_TOTAL 262144
#define D 16
#define TE 3
#define H 64

#define TILES_PER_BLOCK 16
#define FLUSH_GROUP 4
#define NBLOCKS (B_TOTAL / 16 / TILES_PER_BLOCK)   // 1024

#define LOG2E 1.44269504088896340736f
#define LN2   0.693147180559945309417f

// f32 transpose buffer row stride (dwords). 68: keeps ds_read_b128 16B-aligned
// (68*4=272 % 16 == 0) and gives 2-way-max bank aliasing on writes (free).
#define RS 68

typedef _Float16 half8  __attribute__((ext_vector_type(8)));
typedef __fp16   fp16x2 __attribute__((ext_vector_type(2)));   // cvt_pkrtz return type
typedef float    f32x4  __attribute__((ext_vector_type(4)));
typedef unsigned int uint32;

// log2-domain softplus: log2(1 + 2^xs). All scale factors are pre-folded into
// the weights: W1,b1,b2 carry log2e; W3 carries ln2; ln2*log2e==1 so W2 is raw.
__device__ __forceinline__ float sp_log2(float xs) {
    return __builtin_amdgcn_logf(1.0f + __builtin_amdgcn_exp2f(xs));
}
// exact softplus for the final (unscaled) output
__device__ __forceinline__ float softplus_full(float x) {
    float e = __builtin_amdgcn_exp2f(-fabsf(x) * LOG2E);
    return fmaxf(x, 0.0f) + LN2 * __builtin_amdgcn_logf(1.0f + e);
}

// pack 4 floats -> half8 low/high half via v_cvt_pkrtz_f16_f32 (2 floats/instr)
__device__ __forceinline__ half8 pack8(const f32x4 f0, const f32x4 f1) {
    union { half8 h; fp16x2 p[4]; } a;
    a.p[0] = __builtin_amdgcn_cvt_pkrtz(f0.x, f0.y);
    a.p[1] = __builtin_amdgcn_cvt_pkrtz(f0.z, f0.w);
    a.p[2] = __builtin_amdgcn_cvt_pkrtz(f1.x, f1.y);
    a.p[3] = __builtin_amdgcn_cvt_pkrtz(f1.z, f1.w);
    return a.h;
}

// 16 waves/block; wave w owns dim d=w. Per 16-row tile: L1 MFMA (bias folded
// in via constant-1 input column) -> softplus -> f32 LDS transpose -> L2 MFMA
// -> softplus -> same LDS transpose -> L3 MFMA (replicated-column W3 B-frag,
// all C columns == out[b]; no cross-lane reduction needed) -> staged output.
__global__ __launch_bounds__(1024, 4) void DiagonalVariance_kernel(
    const float* __restrict__ t,   // [B, TE]
    const float* __restrict__ y,   // [B, D]
    const float* __restrict__ W1,  // [D, 4, 64]
    const float* __restrict__ b1,  // [D, 64]
    const float* __restrict__ W2,  // [D, 64, 64]
    const float* __restrict__ b2,  // [D, 64]
    const float* __restrict__ W3,  // [D, 64, 1]
    const float* __restrict__ b3,  // [D, 1]
    float* __restrict__ out)       // [B, D]
{
    __shared__ __align__(16) float tbuf[D * 16 * RS];   // 69.6 KB, per-wave slices
    __shared__ float obuf[FLUSH_GROUP * 256];           // 4 KB

    const int wave = threadIdx.x >> 6;   // = d
    const int lane = threadIdx.x & 63;
    const int q    = lane >> 4;
    const int lm   = lane & 15;
    const int d    = wave;
    const bool q0  = (q == 0);

    const float* __restrict__ W1d = W1 + d * (4 * H);
    const float* __restrict__ b1d = b1 + d * H;
    const float* __restrict__ W2d = W2 + d * (H * H);
    const float* __restrict__ b2d = b2 + d * H;
    const float* __restrict__ W3d = W3 + d * H;

    // ---------------- one-time per-wave fragment setup ----------------
    // W2 B-frags (raw): B[n=16nt+lm][k=32ks+8q+j]
    half8 w2f[2][4];
    #pragma unroll
    for (int ks = 0; ks < 2; ++ks)
        #pragma unroll
        for (int nt = 0; nt < 4; ++nt)
            #pragma unroll
            for (int j = 0; j < 8; ++j)
                w2f[ks][nt][j] = (_Float16)W2d[(32 * ks + 8 * q + j) * H + 16 * nt + lm];

    // W1 B-frags (scaled by log2e), with bias b1*log2e in the k=4 row.
    // A-side supplies 1.0 at k=4 -> bias folded into the GEMM, C-init = 0.
    half8 w1f[4];
    #pragma unroll
    for (int nt = 0; nt < 4; ++nt) {
        #pragma unroll
        for (int j = 0; j < 8; ++j) {
            const int h = 16 * nt + lm;
            float v = 0.0f;
            if (q0 && j < 4)  v = W1d[j * H + h] * LOG2E;
            if (q0 && j == 4) v = b1d[h] * LOG2E;
            w1f[nt][j] = (_Float16)v;
        }
    }

    // W3 B-frag (scaled by ln2), replicated across all n columns:
    // B[n][k=32ks+8q+j] = W3[k]*ln2  -> every column of D3 equals out[b].
    half8 w3f[2];
    #pragma unroll
    for (int ks = 0; ks < 2; ++ks)
        #pragma unroll
        for (int j = 0; j < 8; ++j)
            w3f[ks][j] = (_Float16)(W3d[32 * ks + 8 * q + j] * LN2);

    // b2 (scaled) as C-init fragments: col=16nt+lm, replicated over rows.
    f32x4 b2f[4];
    #pragma unroll
    for (int nt = 0; nt < 4; ++nt) {
        const float bv = b2d[16 * nt + lm] * LOG2E;
        b2f[nt] = (f32x4){bv, bv, bv, bv};
    }
    const float b3v = b3[d];

    // LDS transpose bases (per wave slice; all per-tile DS ops use immediate offsets)
    float* const tb  = tbuf + wave * (16 * RS);
    float* const twr = tb + (q * 4) * RS + lm;     // + r*RS + nt*16  (dwords)
    const float* const trd = tb + lm * RS + 8 * q; // + 32*ks + {0,4} (dwords)

    #pragma unroll 1
    for (int g = 0; g < TILES_PER_BLOCK / FLUSH_GROUP; ++g) {
        #pragma unroll 1
        for (int tg = 0; tg < FLUSH_GROUP; ++tg) {
            const int tile = blockIdx.x * TILES_PER_BLOCK + g * FLUSH_GROUP + tg;
            const int row  = tile * 16 + lm;

            // ---- A-frag: k = [y, t0, t1, t2, 1(bias), 0, 0, 0], quad 0 only ----
            const float x0 = y[row * D + d];
            const float t0 = t[row * TE + 0];
            const float t1 = t[row * TE + 1];
            const float t2 = t[row * TE + 2];
            union { half8 h; fp16x2 p[4]; uint32 u[4]; } af;
            const fp16x2 p0 = __builtin_amdgcn_cvt_pkrtz(x0, t0);
            const fp16x2 p1 = __builtin_amdgcn_cvt_pkrtz(t1, t2);
            af.u[0] = q0 ? __builtin_bit_cast(uint32, p0) : 0u;
            af.u[1] = q0 ? __builtin_bit_cast(uint32, p1) : 0u;
            af.u[2] = q0 ? 0x00003C00u : 0u;   // {1.0h, 0h}
            af.u[3] = 0u;

            // ---- layer 1: acc1 = (x*W1 + b1)*log2e, C = 0 ----
            f32x4 acc1[4];
            #pragma unroll
            for (int nt = 0; nt < 4; ++nt)
                acc1[nt] = __builtin_amdgcn_mfma_f32_16x16x32_f16(
                    af.h, w1f[nt], (f32x4){0.f, 0.f, 0.f, 0.f}, 0, 0, 0);

            // ---- softplus (log2 domain) -> f32 LDS transpose (C -> A layout) ----
            #pragma unroll
            for (int nt = 0; nt < 4; ++nt)
                #pragma unroll
                for (int r = 0; r < 4; ++r)
                    twr[r * RS + nt * 16] = sp_log2(acc1[nt][r]);

            // ---- layer-2 A-frags from LDS (b128 reads + packed cvt) ----
            half8 a2[2];
            #pragma unroll
            for (int ks = 0; ks < 2; ++ks) {
                const f32x4 f0 = *(const f32x4*)(trd + 32 * ks);
                const f32x4 f1 = *(const f32x4*)(trd + 32 * ks + 4);
                a2[ks] = pack8(f0, f1);
            }

            // ---- layer 2: C-init = b2*log2e ----
            f32x4 acc2[4];
            #pragma unroll
            for (int nt = 0; nt < 4; ++nt)
                acc2[nt] = __builtin_amdgcn_mfma_f32_16x16x32_f16(a2[0], w2f[0][nt], b2f[nt], 0, 0, 0);
            #pragma unroll
            for (int nt = 0; nt < 4; ++nt)
                acc2[nt] = __builtin_amdgcn_mfma_f32_16x16x32_f16(a2[1], w2f[1][nt], acc2[nt], 0, 0, 0);

            // ---- softplus -> same LDS transpose (buffer reused; same-wave DS order) ----
            #pragma unroll
            for (int nt = 0; nt < 4; ++nt)
                #pragma unroll
                for (int r = 0; r < 4; ++r)
                    twr[r * RS + nt * 16] = sp_log2(acc2[nt][r]);

            half8 a3[2];
            #pragma unroll
            for (int ks = 0; ks < 2; ++ks) {
                const f32x4 f0 = *(const f32x4*)(trd + 32 * ks);
                const f32x4 f1 = *(const f32x4*)(trd + 32 * ks + 4);
                a3[ks] = pack8(f0, f1);
            }

            // ---- layer 3: every column n of D3 = sum_k L[b,k]*W3[k]*ln2 ----
            f32x4 acc3;
            acc3 = __builtin_amdgcn_mfma_f32_16x16x32_f16(a3[0], w3f[0], (f32x4){0.f, 0.f, 0.f, 0.f}, 0, 0, 0);
            acc3 = __builtin_amdgcn_mfma_f32_16x16x32_f16(a3[1], w3f[1], acc3, 0, 0, 0);

            // lane lm<4 takes reg r=lm -> row q*4+lm; all 16 rows covered.
            const float v01 = (lm & 1) ? acc3[1] : acc3[0];
            const float v23 = (lm & 1) ? acc3[3] : acc3[2];
            const float vs  = (lm & 2) ? v23 : v01;
            if (lm < 4)
                obuf[tg * 256 + (q * 4 + lm) * D + d] = softplus_full(vs + b3v);
        }

        __syncthreads();
        // coalesced flush: 1024 contiguous floats = 4 tiles x 16 rows x 16 d
        out[blockIdx.x * (TILES_PER_BLOCK * 256) + g * 1024 + threadIdx.x] = obuf[threadIdx.x];
        __syncthreads();
    }
}

extern "C" void kernel_launch(void* const* d_in, const int* in_sizes, int n_in,
                              void* d_out, int out_size, void* d_ws, size_t ws_size,
                              hipStream_t stream) {
    const float* t  = (const float*)d_in[0];
    const float* y  = (const float*)d_in[1];
    const float* W1 = (const float*)d_in[2];
    const float* b1 = (const float*)d_in[3];
    const float* W2 = (const float*)d_in[4];
    const float* b2 = (const float*)d_in[5];
    const float* W3 = (const float*)d_in[6];
    const float* b3 = (const float*)d_in[7];
    float* out = (float*)d_out;

    DiagonalVariance_kernel<<<dim3(NBLOCKS), dim3(1024), 0, stream>>>(
        t, y, W1, b1, W2, b2, W3, b3, out);
}